// Round 7
// baseline (251.453 us; speedup 1.0000x reference)
//
#include <hip/hip_runtime.h>
#include <math.h>

#define BLOCK 256
// Layer cell counts (b=32, 3 anchors):
//  L0: 32*3*13*13 = 16224  -> 64 blocks   (13x13, anchors 6,7,8)
//  L1: 32*3*26*26 = 64896  -> 254 blocks  (26x26, anchors 3,4,5)
//  L2: 32*3*52*52 = 259584 -> 1014 blocks (52x52, anchors 0,1,2)
#define NB0 64
#define NB1 254
#define NB2 1014
#define NBLOCKS (NB0 + NB1 + NB2)

// 4-byte-aligned float4 (only for target loads: 20B stride, L1-resident broadcast)
typedef float f4a __attribute__((ext_vector_type(4), aligned(4)));

// anchors ordered [layer][a]: layer0 = ANCHORS[6,7,8], layer1 = [3,4,5], layer2 = [0,1,2]
__constant__ float c_anch[9][2] = {
    {116.f, 90.f}, {156.f, 198.f}, {373.f, 326.f},
    { 30.f, 61.f}, { 62.f,  45.f}, { 59.f, 119.f},
    { 10.f, 13.f}, { 16.f,  30.f}, { 33.f,  23.f}
};

// stable softplus: log(1+exp(x)) = max(x,0) + log(1+exp(-|x|))
__device__ __forceinline__ float softplusf(float x) {
    float ax = fabsf(x);
    return fmaxf(x, 0.f) + __logf(1.f + __expf(-ax));
}

__device__ __forceinline__ float sigmoidf(float x) {
    return __fdividef(1.f, 1.f + __expf(-x));
}

// ---- wave-private y_true staging (NO __syncthreads: a wave's ds_writes are
// visible to itself via the in-order DS pipe + compiler lgkmcnt waits). ----
// Class chunk Q = y_true channels [5+16Q, 5+16Q+16) for this wave's 64 cells.
// Stage mapping: instr k, lane l -> cell = k*4 + (l>>4), ch = l&15:
// 64 lanes cover 4 x 64B contiguous runs (stride 340B) — coalesced.

template<int Q>
__device__ __forceinline__ void stage_cls(const float* __restrict__ tw, int lane,
                                          int nvc, bool full, float* r) {
    if (full) {
        int lo = (lane >> 4) * 85 + (lane & 15);
#pragma unroll
        for (int k = 0; k < 16; k++)
            r[k] = tw[lo + k * 340 + 5 + Q * 16];
    } else {
        // exactly one wave in the whole grid takes this path (L0 blk63 wv1)
#pragma unroll
        for (int k = 0; k < 16; k++) {
            int cc = min(k * 4 + (lane >> 4), nvc - 1);
            r[k] = tw[cc * 85 + (lane & 15) + 5 + Q * 16];
        }
    }
}

__device__ __forceinline__ void write_cls(float (*S)[17], int lane, const float* r) {
#pragma unroll
    for (int k = 0; k < 16; k++)
        S[k * 4 + (lane >> 4)][lane & 15] = r[k];
}

// One class phase (MLP-batched):
//   1. batch-issue 16 pred loads for chunk Q into x[16]   (16 outstanding vmem)
//   2. sched_barrier: nothing crosses — loads stay issued FIRST
//   3. ds_write chunk-Q y_true (vmcnt wait for creg leaves pred batch in flight)
//   4. issue chunk-(Q+1) y_true loads                      (overlap pred wait)
//   5. sched_barrier, then compute (vmcnt wait for pred leaves trues in flight)
template<int Q>
__device__ __forceinline__ void class_phase(const float* __restrict__ tw,
                                            const float* __restrict__ pb,
                                            float (*S)[17], int lane, int nvc,
                                            bool full, int hw, float* creg,
                                            float& cls, bool active) {
    float x[16];
    if (active) {
#pragma unroll
        for (int c = 0; c < 16; c++)
            x[c] = pb[(size_t)((5 + Q * 16 + c) * hw)];   // lane-coalesced 256B
    }
    __builtin_amdgcn_sched_barrier(0);
    write_cls(S, lane, creg);
    if constexpr (Q < 4)
        stage_cls<Q + 1>(tw, lane, nvc, full, creg);
    __builtin_amdgcn_sched_barrier(0);
    if (active) {
#pragma unroll
        for (int c = 0; c < 16; c++) {
            float t = S[lane][c];          // stride-17: 2-way bank alias = free
            cls += softplusf(x[c]) - t * x[c];
        }
    }
}

// __launch_bounds__(256,6): 6 blocks/CU capacity (24 waves/CU) >= the grid's
// 5.2 blocks/CU average -> WHOLE GRID CO-RESIDENT, no drain tail. R6's bound
// of 4 left 308 of 1332 blocks in a ~30%-loaded second round (occupancy 33%,
// ~1.3x makespan inflation). VGPR at R6's structure is 52 — fits the ~85 cap.
__global__ __launch_bounds__(BLOCK, 6) void yolo_loss_main(
    const float* __restrict__ p0, const float* __restrict__ p1, const float* __restrict__ p2,
    const float* __restrict__ t0, const float* __restrict__ t1, const float* __restrict__ t2,
    const float* __restrict__ tgt, float* __restrict__ partials)
{
    // per-wave private tiles -> no cross-wave coordination, no barriers
    __shared__ float sh[4][64][17];   // 17408 B -> LDS allows 8 blocks/CU

    int blk = blockIdx.x;
    const float* pred;
    const float* tru;
    int layer, g, cells, bbase;
    if (blk < NB0)            { layer = 0; pred = p0; tru = t0; g = 13; cells = 16224;  bbase = 0; }
    else if (blk < NB0 + NB1) { layer = 1; pred = p1; tru = t1; g = 26; cells = 64896;  bbase = NB0; }
    else                      { layer = 2; pred = p2; tru = t2; g = 52; cells = 259584; bbase = NB0 + NB1; }

    int tid = threadIdx.x;
    int lane = tid & 63;
    int wv = tid >> 6;
    int cell0 = (blk - bbase) * BLOCK + wv * 64;   // this wave's first cell
    int nv = cells - cell0;                        // valid cells for this wave
    float acc = 0.f;

    if (nv > 0) {                                  // wave-uniform branch
        float (*S)[17] = sh[wv];
        bool full = (nv >= 64);
        int nvc = full ? 64 : nv;
        bool active = lane < nv;
        const float* tw = tru + (size_t)cell0 * 85;

        int cidx = active ? (cell0 + lane) : (cells - 1);
        int hw = g * g;
        int ij = cidx % hw;
        int a  = (cidx / hw) % 3;
        int b  = cidx / (3 * hw);
        int i  = ij / g;
        int j  = ij - i * g;
        // raw[b][a][i][j][c] = y_pred[b][a*85+c][i][j] (channel stride hw, coalesced)
        const float* pb = pred + (size_t)((b * 3 + a) * 85) * hw + ij;

        // ---- stage head: ch 0..4 x 64 cells, flat f = cell*5+ch mapping ----
        {
            float hreg[5];
#pragma unroll
            for (int k = 0; k < 5; k++) {
                int f = k * 64 + lane;
                int cell = f / 5;
                int ch = f - cell * 5;
                int cc = full ? cell : min(cell, nvc - 1);
                hreg[k] = tw[cc * 85 + ch];
            }
#pragma unroll
            for (int k = 0; k < 5; k++) {
                int f = k * 64 + lane;
                int cell = f / 5;
                int ch = f - cell * 5;
                S[cell][ch] = hreg[k];
            }
        }

        float creg[16];
        stage_cls<0>(tw, lane, nvc, full, creg);   // chunk0 latency hides under head

        float cls = 0.f, mask = 0.f;
        if (active) {
            float y0 = S[lane][0], y1 = S[lane][1], y2 = S[lane][2], y3 = S[lane][3];
            mask = S[lane][4];

            float r0 = pb[0];
            float r1 = pb[hw];
            float r2 = pb[2 * hw];
            float r3 = pb[3 * hw];
            float r4 = pb[4 * hw];

            float gf = (float)g, gx = (float)j, gy = (float)i;
            float aw = c_anch[layer * 3 + a][0];
            float ah = c_anch[layer * 3 + a][1];

            // xy loss: bce(sigmoid(r), t) = softplus(r) - t*r
            float true_x = y0 * gf - gx;
            float true_y = y1 * gf - gy;
            float ls = 2.f - y2 * y3;   // loss_scale
            float lxy = (softplusf(r0) - true_x * r0) + (softplusf(r1) - true_y * r1);
            acc += mask * ls * lxy;

            // wh loss
            float tw_ = __logf(y2 * (416.f / aw));
            float th_ = __logf(y3 * (416.f / ah));
            float dw = r2 - tw_, dh = r3 - th_;
            acc += mask * ls * 0.5f * (dw * dw + dh * dh);

            // conf bce
            float cbce = softplusf(r4) - mask * r4;

            // IoU vs 20 targets -> neg mask
            float sx = sigmoidf(r0);
            float sy = sigmoidf(r1);
            float bx = __fdividef(sx + gx, gf);
            float by = __fdividef(sy + gy, gf);
            float bw = __expf(r2) * aw * (1.f / 416.f);
            float bh = __expf(r3) * ah * (1.f / 416.f);
            float a1 = bw * bh;
            float b1minx = bx - 0.5f * bw, b1maxx = bx + 0.5f * bw;
            float b1miny = by - 0.5f * bh, b1maxy = by + 0.5f * bh;

            const float* tg = tgt + b * 20 * 5;
            float best = 0.f;
#pragma unroll 5
            for (int k = 0; k < 20; k++) {
                f4a t = *reinterpret_cast<const f4a*>(tg + k * 5);  // tx,ty,tw,th
                float hw2 = 0.5f * t.z, hh2 = 0.5f * t.w;
                float iw = fminf(b1maxx, t.x + hw2) - fmaxf(b1minx, t.x - hw2);
                float ih = fminf(b1maxy, t.y + hh2) - fmaxf(b1miny, t.y - hh2);
                iw = fmaxf(iw, 0.f);
                ih = fmaxf(ih, 0.f);
                float inter = iw * ih;
                float iou = __fdividef(inter, a1 + t.z * t.w - inter);
                best = fmaxf(best, iou);
            }
            float neg = (best < 0.5f) ? 1.f : 0.f;
            acc += mask * cbce + (1.f - mask) * neg * cbce;
        }

        // ---- class chunks: batched pred loads, overlapped staging ----
        class_phase<0>(tw, pb, S, lane, nvc, full, hw, creg, cls, active);
        class_phase<1>(tw, pb, S, lane, nvc, full, hw, creg, cls, active);
        class_phase<2>(tw, pb, S, lane, nvc, full, hw, creg, cls, active);
        class_phase<3>(tw, pb, S, lane, nvc, full, hw, creg, cls, active);
        class_phase<4>(tw, pb, S, lane, nvc, full, hw, creg, cls, active);

        if (active) acc += mask * cls;
    }

    // ---- block reduction: wave shuffle then LDS (only barrier in the kernel) ----
    for (int off = 32; off > 0; off >>= 1)
        acc += __shfl_down(acc, off, 64);
    __shared__ float shr[BLOCK / 64];
    if ((threadIdx.x & 63) == 0)
        shr[threadIdx.x >> 6] = acc;
    __syncthreads();
    if (threadIdx.x == 0) {
        float s = 0.f;
        for (int w = 0; w < BLOCK / 64; w++) s += shr[w];
        partials[blockIdx.x] = s;
    }
}

__global__ __launch_bounds__(BLOCK) void yolo_loss_reduce(
    const float* __restrict__ partials, float* __restrict__ out)
{
    float s = 0.f;
    for (int i = threadIdx.x; i < NBLOCKS; i += BLOCK)
        s += partials[i];
    for (int off = 32; off > 0; off >>= 1)
        s += __shfl_down(s, off, 64);
    __shared__ float sh[BLOCK / 64];
    if ((threadIdx.x & 63) == 0)
        sh[threadIdx.x >> 6] = s;
    __syncthreads();
    if (threadIdx.x == 0) {
        float tot = 0.f;
        for (int wv = 0; wv < BLOCK / 64; wv++) tot += sh[wv];
        out[0] = tot;
    }
}

extern "C" void kernel_launch(void* const* d_in, const int* in_sizes, int n_in,
                              void* d_out, int out_size, void* d_ws, size_t ws_size,
                              hipStream_t stream) {
    // setup_inputs() dict order is INTERLEAVED:
    //   d_in[0]=y_pred0, d_in[1]=y_true0, d_in[2]=y_pred1, d_in[3]=y_true1,
    //   d_in[4]=y_pred2, d_in[5]=y_true2, d_in[6]=target
    const float* p0  = (const float*)d_in[0];
    const float* t0  = (const float*)d_in[1];
    const float* p1  = (const float*)d_in[2];
    const float* t1  = (const float*)d_in[3];
    const float* p2  = (const float*)d_in[4];
    const float* t2  = (const float*)d_in[5];
    const float* tgt = (const float*)d_in[6];
    float* partials  = (float*)d_ws;   // NBLOCKS floats; every slot written each call

    yolo_loss_main<<<NBLOCKS, BLOCK, 0, stream>>>(p0, p1, p2, t0, t1, t2, tgt, partials);
    yolo_loss_reduce<<<1, BLOCK, 0, stream>>>(partials, (float*)d_out);
}

// Round 8
// 249.419 us; speedup vs baseline: 1.0082x; 1.0082x over previous
//
#include <hip/hip_runtime.h>
#include <math.h>

#define BLOCK 256
// Layer cell counts (b=32, 3 anchors):
//  L0: 32*3*13*13 = 16224  -> 64 blocks   (13x13, anchors 6,7,8)
//  L1: 32*3*26*26 = 64896  -> 254 blocks  (26x26, anchors 3,4,5)
//  L2: 32*3*52*52 = 259584 -> 1014 blocks (52x52, anchors 0,1,2)
#define NB0 64
#define NB1 254
#define NB2 1014
#define NBLOCKS (NB0 + NB1 + NB2)

// 4-byte-aligned float4 (only for target loads: 20B stride, L1-resident broadcast)
typedef float f4a __attribute__((ext_vector_type(4), aligned(4)));

// anchors ordered [layer][a]: layer0 = ANCHORS[6,7,8], layer1 = [3,4,5], layer2 = [0,1,2]
__constant__ float c_anch[9][2] = {
    {116.f, 90.f}, {156.f, 198.f}, {373.f, 326.f},
    { 30.f, 61.f}, { 62.f,  45.f}, { 59.f, 119.f},
    { 10.f, 13.f}, { 16.f,  30.f}, { 33.f,  23.f}
};

// stable softplus: log(1+exp(x)) = max(x,0) + log(1+exp(-|x|))
__device__ __forceinline__ float softplusf(float x) {
    float ax = fabsf(x);
    return fmaxf(x, 0.f) + __logf(1.f + __expf(-ax));
}

__device__ __forceinline__ float sigmoidf(float x) {
    return __fdividef(1.f, 1.f + __expf(-x));
}

// ---- wave-private y_true staging (NO __syncthreads: a wave's ds_writes are
// visible to itself via the in-order DS pipe + compiler lgkmcnt waits). ----
// Class chunk Q = y_true channels [5+16Q, 5+16Q+16) for this wave's 64 cells.
// Stage mapping: instr k, lane l -> cell = k*4 + (l>>4), ch = l&15:
// 64 lanes cover 4 x 64B contiguous runs (stride 340B) — coalesced.

template<int Q>
__device__ __forceinline__ void stage_cls(const float* __restrict__ tw, int lane,
                                          int nvc, bool full, float* r) {
    if (full) {
        int lo = (lane >> 4) * 85 + (lane & 15);
#pragma unroll
        for (int k = 0; k < 16; k++)
            r[k] = tw[lo + k * 340 + 5 + Q * 16];
    } else {
        // exactly one wave in the whole grid takes this path (L0 blk63 wv1)
#pragma unroll
        for (int k = 0; k < 16; k++) {
            int cc = min(k * 4 + (lane >> 4), nvc - 1);
            r[k] = tw[cc * 85 + (lane & 15) + 5 + Q * 16];
        }
    }
}

__device__ __forceinline__ void write_cls(float (*S)[17], int lane, const float* r) {
#pragma unroll
    for (int k = 0; k < 16; k++)
        S[k * 4 + (lane >> 4)][lane & 15] = r[k];
}

// batch-issue the 16 pred loads for class chunk Q (lane-coalesced 256B each)
template<int Q>
__device__ __forceinline__ void load_x(const float* __restrict__ pb, int hw,
                                       bool active, float* x) {
    if (active) {
#pragma unroll
        for (int c = 0; c < 16; c++)
            x[c] = pb[(size_t)((5 + Q * 16 + c) * hw)];
    }
}

// One class phase, fully software-pipelined:
//   xcur  = pred chunk Q,     ISSUED A FULL PHASE AGO  -> landed, no wait
//   creg  = y_true chunk Q,   issued a phase ago       -> landed, cheap vmcnt
//   1. ds_write creg -> S
//   2. issue y_true chunk Q+1 (creg) and pred chunk Q+1 (xnext)
//   3. sched_barrier: issues stay ABOVE the consume
//   4. consume: softplus(xcur) vs S  — no global round-trip on critical path
template<int Q>
__device__ __forceinline__ void class_phase(const float* __restrict__ tw,
                                            const float* __restrict__ pb,
                                            float (*S)[17], int lane, int nvc,
                                            bool full, int hw, float* creg,
                                            float* xcur, float* xnext,
                                            float& cls, bool active) {
    write_cls(S, lane, creg);
    if constexpr (Q < 4) {
        stage_cls<Q + 1>(tw, lane, nvc, full, creg);
        load_x<Q + 1>(pb, hw, active, xnext);
    }
    __builtin_amdgcn_sched_barrier(0);
    if (active) {
#pragma unroll
        for (int c = 0; c < 16; c++) {
            float t = S[lane][c];          // stride-17: 2-way bank alias = free
            cls += softplusf(xcur[c]) - t * xcur[c];
        }
    }
    __builtin_amdgcn_sched_barrier(0);
}

// __launch_bounds__(256,4): KEEP AT 4. R7 proved the 2nd arg is the compiler's
// schedule-depth knob: bounds 6 -> VGPR 40, re-serialized loads, 109us; bounds
// 4 -> VGPR cap 128, deep batches, 96.6us. Occupancy does NOT help this kernel
// (R4 50% occ == R0 39% occ == 108us); per-wave MLP does.
__global__ __launch_bounds__(BLOCK, 4) void yolo_loss_main(
    const float* __restrict__ p0, const float* __restrict__ p1, const float* __restrict__ p2,
    const float* __restrict__ t0, const float* __restrict__ t1, const float* __restrict__ t2,
    const float* __restrict__ tgt, float* __restrict__ partials)
{
    // per-wave private tiles -> no cross-wave coordination, no barriers
    __shared__ float sh[4][64][17];   // 17408 B

    int blk = blockIdx.x;
    const float* pred;
    const float* tru;
    int layer, g, cells, bbase;
    if (blk < NB0)            { layer = 0; pred = p0; tru = t0; g = 13; cells = 16224;  bbase = 0; }
    else if (blk < NB0 + NB1) { layer = 1; pred = p1; tru = t1; g = 26; cells = 64896;  bbase = NB0; }
    else                      { layer = 2; pred = p2; tru = t2; g = 52; cells = 259584; bbase = NB0 + NB1; }

    int tid = threadIdx.x;
    int lane = tid & 63;
    int wv = tid >> 6;
    int cell0 = (blk - bbase) * BLOCK + wv * 64;   // this wave's first cell
    int nv = cells - cell0;                        // valid cells for this wave
    float acc = 0.f;

    if (nv > 0) {                                  // wave-uniform branch
        float (*S)[17] = sh[wv];
        bool full = (nv >= 64);
        int nvc = full ? 64 : nv;
        bool active = lane < nv;
        const float* tw = tru + (size_t)cell0 * 85;

        int cidx = active ? (cell0 + lane) : (cells - 1);
        int hw = g * g;
        int ij = cidx % hw;
        int a  = (cidx / hw) % 3;
        int b  = cidx / (3 * hw);
        int i  = ij / g;
        int j  = ij - i * g;
        // raw[b][a][i][j][c] = y_pred[b][a*85+c][i][j] (channel stride hw, coalesced)
        const float* pb = pred + (size_t)((b * 3 + a) * 85) * hw + ij;

        float creg[16], xA[16], xB[16];

        // ---- head stage + EARLY ISSUE of chunk-0 streams ----
        float hreg[5];
#pragma unroll
        for (int k = 0; k < 5; k++) {
            int f = k * 64 + lane;
            int cell = f / 5;
            int ch = f - cell * 5;
            int cc = full ? cell : min(cell, nvc - 1);
            hreg[k] = tw[cc * 85 + ch];
        }
        stage_cls<0>(tw, lane, nvc, full, creg);   // y_true chunk 0 in flight
        load_x<0>(pb, hw, active, xA);             // pred chunk 0 in flight
        __builtin_amdgcn_sched_barrier(0);
        // write head (compiler's counted vmcnt waits hreg only; creg/xA younger,
        // stay outstanding under the whole head-consume stretch below)
#pragma unroll
        for (int k = 0; k < 5; k++) {
            int f = k * 64 + lane;
            int cell = f / 5;
            int ch = f - cell * 5;
            S[cell][ch] = hreg[k];
        }

        float cls = 0.f, mask = 0.f;
        if (active) {
            float y0 = S[lane][0], y1 = S[lane][1], y2 = S[lane][2], y3 = S[lane][3];
            mask = S[lane][4];

            float r0 = pb[0];
            float r1 = pb[hw];
            float r2 = pb[2 * hw];
            float r3 = pb[3 * hw];
            float r4 = pb[4 * hw];

            float gf = (float)g, gx = (float)j, gy = (float)i;
            float aw = c_anch[layer * 3 + a][0];
            float ah = c_anch[layer * 3 + a][1];

            // xy loss: bce(sigmoid(r), t) = softplus(r) - t*r
            float true_x = y0 * gf - gx;
            float true_y = y1 * gf - gy;
            float ls = 2.f - y2 * y3;   // loss_scale
            float lxy = (softplusf(r0) - true_x * r0) + (softplusf(r1) - true_y * r1);
            acc += mask * ls * lxy;

            // wh loss
            float tw_ = __logf(y2 * (416.f / aw));
            float th_ = __logf(y3 * (416.f / ah));
            float dw = r2 - tw_, dh = r3 - th_;
            acc += mask * ls * 0.5f * (dw * dw + dh * dh);

            // conf bce
            float cbce = softplusf(r4) - mask * r4;

            // IoU vs 20 targets -> neg mask (tgt is wave-uniform, L1-resident)
            float sx = sigmoidf(r0);
            float sy = sigmoidf(r1);
            float bx = __fdividef(sx + gx, gf);
            float by = __fdividef(sy + gy, gf);
            float bw = __expf(r2) * aw * (1.f / 416.f);
            float bh = __expf(r3) * ah * (1.f / 416.f);
            float a1 = bw * bh;
            float b1minx = bx - 0.5f * bw, b1maxx = bx + 0.5f * bw;
            float b1miny = by - 0.5f * bh, b1maxy = by + 0.5f * bh;

            const float* tg = tgt + b * 20 * 5;
            float best = 0.f;
#pragma unroll 5
            for (int k = 0; k < 20; k++) {
                f4a t = *reinterpret_cast<const f4a*>(tg + k * 5);  // tx,ty,tw,th
                float hw2 = 0.5f * t.z, hh2 = 0.5f * t.w;
                float iw = fminf(b1maxx, t.x + hw2) - fmaxf(b1minx, t.x - hw2);
                float ih = fminf(b1maxy, t.y + hh2) - fmaxf(b1miny, t.y - hh2);
                iw = fmaxf(iw, 0.f);
                ih = fmaxf(ih, 0.f);
                float inter = iw * ih;
                float iou = __fdividef(inter, a1 + t.z * t.w - inter);
                best = fmaxf(best, iou);
            }
            float neg = (best < 0.5f) ? 1.f : 0.f;
            acc += mask * cbce + (1.f - mask) * neg * cbce;
        }

        // ---- class chunks: double-buffered pred stream (xA/xB by parity) ----
        class_phase<0>(tw, pb, S, lane, nvc, full, hw, creg, xA, xB, cls, active);
        class_phase<1>(tw, pb, S, lane, nvc, full, hw, creg, xB, xA, cls, active);
        class_phase<2>(tw, pb, S, lane, nvc, full, hw, creg, xA, xB, cls, active);
        class_phase<3>(tw, pb, S, lane, nvc, full, hw, creg, xB, xA, cls, active);
        class_phase<4>(tw, pb, S, lane, nvc, full, hw, creg, xA, xB, cls, active);

        if (active) acc += mask * cls;
    }

    // ---- block reduction: wave shuffle then LDS (only barrier in the kernel) ----
    for (int off = 32; off > 0; off >>= 1)
        acc += __shfl_down(acc, off, 64);
    __shared__ float shr[BLOCK / 64];
    if ((threadIdx.x & 63) == 0)
        shr[threadIdx.x >> 6] = acc;
    __syncthreads();
    if (threadIdx.x == 0) {
        float s = 0.f;
        for (int w = 0; w < BLOCK / 64; w++) s += shr[w];
        partials[blockIdx.x] = s;
    }
}

__global__ __launch_bounds__(BLOCK) void yolo_loss_reduce(
    const float* __restrict__ partials, float* __restrict__ out)
{
    float s = 0.f;
    for (int i = threadIdx.x; i < NBLOCKS; i += BLOCK)
        s += partials[i];
    for (int off = 32; off > 0; off >>= 1)
        s += __shfl_down(s, off, 64);
    __shared__ float sh[BLOCK / 64];
    if ((threadIdx.x & 63) == 0)
        sh[threadIdx.x >> 6] = s;
    __syncthreads();
    if (threadIdx.x == 0) {
        float tot = 0.f;
        for (int wv = 0; wv < BLOCK / 64; wv++) tot += sh[wv];
        out[0] = tot;
    }
}

extern "C" void kernel_launch(void* const* d_in, const int* in_sizes, int n_in,
                              void* d_out, int out_size, void* d_ws, size_t ws_size,
                              hipStream_t stream) {
    // setup_inputs() dict order is INTERLEAVED:
    //   d_in[0]=y_pred0, d_in[1]=y_true0, d_in[2]=y_pred1, d_in[3]=y_true1,
    //   d_in[4]=y_pred2, d_in[5]=y_true2, d_in[6]=target
    const float* p0  = (const float*)d_in[0];
    const float* t0  = (const float*)d_in[1];
    const float* p1  = (const float*)d_in[2];
    const float* t1  = (const float*)d_in[3];
    const float* p2  = (const float*)d_in[4];
    const float* t2  = (const float*)d_in[5];
    const float* tgt = (const float*)d_in[6];
    float* partials  = (float*)d_ws;   // NBLOCKS floats; every slot written each call

    yolo_loss_main<<<NBLOCKS, BLOCK, 0, stream>>>(p0, p1, p2, t0, t1, t2, tgt, partials);
    yolo_loss_reduce<<<1, BLOCK, 0, stream>>>(partials, (float*)d_out);
}